// Round 1
// baseline (124.038 us; speedup 1.0000x reference)
//
#include <hip/hip_runtime.h>
#include <hip/hip_bf16.h>

// Problem constants
#define B_N 64
#define H_IMG 1024
#define W_IMG 1024
#define G_SZ 64
#define K_SC 3
#define D_IN 12288      // K*G*G
#define HG0 512
#define OUT_N 1024      // HG0+HL
#define SPLITK 64
#define DCHUNK 192      // D_IN / SPLITK

// ---------------- Foveation: phiT[d*64 + b] ----------------
// d = k*4096 + gy*64 + gx ; patch k: size=256>>k, pool r=4>>k
__global__ __launch_bounds__(256) void foveate_kernel(
    const float* __restrict__ x, const float* __restrict__ l,
    float* __restrict__ phiT) {
  int idx = blockIdx.x * 256 + threadIdx.x;      // < 64*12288
  int b = idx / D_IN;
  int d = idx - b * D_IN;
  int k = d >> 12;
  int rem = d & 4095;
  int gy = rem >> 6, gx = rem & 63;

  float lx = l[b * 2 + 0];
  float ly = l[b * 2 + 1];
  // match: (0.5 * ((l + 1.0) * H)).astype(int32)  (truncation)
  int cx = (int)(0.5f * ((lx + 1.0f) * 1024.0f));
  int cy = (int)(0.5f * ((ly + 1.0f) * 1024.0f));

  int r = 4 >> k;                // 4,2,1
  int half = 128 >> k;           // size/2 = 128,64,32
  int y0 = cy - half + gy * r;
  int x0 = cx - half + gx * r;

  const float* xb = x + ((size_t)b << 20);
  float s = 0.0f;
  for (int dy = 0; dy < r; ++dy) {
    int yy = y0 + dy;
    if ((unsigned)yy < 1024u) {
      const float* row = xb + ((size_t)yy << 10);
      for (int dx = 0; dx < r; ++dx) {
        int xx = x0 + dx;
        if ((unsigned)xx < 1024u) s += row[xx];
      }
    }
  }
  float inv = (r == 4) ? 0.0625f : (r == 2) ? 0.25f : 1.0f;
  phiT[(size_t)d * 64 + b] = s * inv;
}

// ---------------- GEMM1 split-K: partial[kc][j*64+b] ----------------
// grid (16, SPLITK), block 256 (4 waves; wave w owns j's [bx*32+w*8, +8))
__global__ __launch_bounds__(256) void gemm1_kernel(
    const float* __restrict__ phiT, const float* __restrict__ W1,
    float* __restrict__ partial) {
  int wave = threadIdx.x >> 6;
  int lane = threadIdx.x & 63;              // = b
  int j0 = blockIdx.x * 32 + wave * 8;
  int d0 = blockIdx.y * DCHUNK;

  float acc[8] = {0.f, 0.f, 0.f, 0.f, 0.f, 0.f, 0.f, 0.f};
  const float* wp = W1 + (size_t)j0 * D_IN;

  #pragma unroll 4
  for (int d = d0; d < d0 + DCHUNK; ++d) {
    float pv = phiT[(size_t)d * 64 + lane];
    #pragma unroll
    for (int jj = 0; jj < 8; ++jj)
      acc[jj] = fmaf(pv, wp[(size_t)jj * D_IN + d], acc[jj]);
  }

  float* pp = partial + (size_t)blockIdx.y * (HG0 * 64) + (size_t)j0 * 64 + lane;
  #pragma unroll
  for (int jj = 0; jj < 8; ++jj) pp[(size_t)jj * 64] = acc[jj];
}

// ---------------- reduce split-K + leaky_relu -> hT[j*64+b] ----------------
__global__ __launch_bounds__(256) void reduce_kernel(
    const float* __restrict__ partial, float* __restrict__ hT) {
  int idx = blockIdx.x * 256 + threadIdx.x;   // < 32768
  float s = 0.0f;
  #pragma unroll 8
  for (int kc = 0; kc < SPLITK; ++kc) s += partial[(size_t)kc * (HG0 * 64) + idx];
  hT[idx] = (s >= 0.0f) ? s : 0.01f * s;
}

// ---------------- GEMM2: out[b][o] = lrelu( sum_j h[b][j]*(W3[o][j]+W4[o][j]) ) --
// grid 256, block 64 (lane=b); each block computes 4 consecutive o's
__global__ __launch_bounds__(64) void gemm2_kernel(
    const float* __restrict__ hT, const float* __restrict__ W3,
    const float* __restrict__ W4, float* __restrict__ out) {
  int lane = threadIdx.x;          // = b
  int o0 = blockIdx.x * 4;
  float acc[4] = {0.f, 0.f, 0.f, 0.f};

  #pragma unroll 4
  for (int j = 0; j < HG0; ++j) {
    float hv = hT[(size_t)j * 64 + lane];
    #pragma unroll
    for (int oo = 0; oo < 4; ++oo) {
      float w = W3[(size_t)(o0 + oo) * HG0 + j] + W4[(size_t)(o0 + oo) * HG0 + j];
      acc[oo] = fmaf(hv, w, acc[oo]);
    }
  }
  #pragma unroll
  for (int oo = 0; oo < 4; ++oo) {
    float v = acc[oo];
    out[(size_t)lane * OUT_N + o0 + oo] = (v >= 0.0f) ? v : 0.01f * v;
  }
}

extern "C" void kernel_launch(void* const* d_in, const int* in_sizes, int n_in,
                              void* d_out, int out_size, void* d_ws, size_t ws_size,
                              hipStream_t stream) {
  const float* x  = (const float*)d_in[0];   // (64,1,1024,1024)
  const float* l  = (const float*)d_in[1];   // (64,2)
  const float* W1 = (const float*)d_in[2];   // (512,12288)
  // d_in[3] = W2, unused (reference computes l_out but discards it)
  const float* W3 = (const float*)d_in[4];   // (1024,512)
  const float* W4 = (const float*)d_in[5];   // (1024,512)
  float* out = (float*)d_out;                // (64,1024)

  float* ws = (float*)d_ws;
  float* phiT    = ws;                                   // 786432 floats (3 MB)
  float* partial = ws + (size_t)D_IN * 64;               // 64*32768 floats (8 MB)
  float* hT      = partial + (size_t)SPLITK * HG0 * 64;  // 32768 floats

  foveate_kernel<<<dim3((B_N * D_IN) / 256), dim3(256), 0, stream>>>(x, l, phiT);
  gemm1_kernel<<<dim3(16, SPLITK), dim3(256), 0, stream>>>(phiT, W1, partial);
  reduce_kernel<<<dim3((HG0 * 64) / 256), dim3(256), 0, stream>>>(partial, hT);
  gemm2_kernel<<<dim3(OUT_N / 4), dim3(64), 0, stream>>>(hT, W3, W4, out);
}

// Round 2
// 35.489 us; speedup vs baseline: 3.4951x; 3.4951x over previous
//
#include <hip/hip_runtime.h>
#include <hip/hip_bf16.h>

#define B_N 64
#define D_IN 12288      // K*G*G
#define HG0 512
#define OUT_N 1024      // HG0+HL

// GEMM1 split-K
#define KC1 64
#define DCHUNK1 192     // D_IN / KC1 (6 k-steps of 32)
// GEMM2 split-K
#define KC2 8
#define DCHUNK2 64      // HG0 / KC2 (2 k-steps of 32)

typedef __attribute__((ext_vector_type(8))) short bf16x8;
typedef __attribute__((ext_vector_type(4))) float f32x4;

static __device__ __forceinline__ short f2bf(float f) {
  __hip_bfloat16 h = __float2bfloat16(f);
  return *reinterpret_cast<short*>(&h);
}

// ---------------- Foveation -> phi_bf16[b][12288] ----------------
__global__ __launch_bounds__(256) void foveate_kernel(
    const float* __restrict__ x, const float* __restrict__ l,
    short* __restrict__ phi) {
  int idx = blockIdx.x * 256 + threadIdx.x;   // b*D_IN + d
  int b = idx / D_IN;
  int d = idx - b * D_IN;
  int k = d >> 12;
  int rem = d & 4095;
  int gy = rem >> 6, gx = rem & 63;

  float lx = l[b * 2 + 0];
  float ly = l[b * 2 + 1];
  int cx = (int)(0.5f * ((lx + 1.0f) * 1024.0f));   // trunc, matches .astype(int32)
  int cy = (int)(0.5f * ((ly + 1.0f) * 1024.0f));

  int r = 4 >> k;                 // 4,2,1
  int half = 128 >> k;            // 128,64,32
  int y0 = cy - half + gy * r;
  int x0 = cx - half + gx * r;

  const float* xb = x + ((size_t)b << 20);
  float s = 0.0f;
  for (int dy = 0; dy < r; ++dy) {
    int yy = y0 + dy;
    if ((unsigned)yy < 1024u) {
      const float* row = xb + ((size_t)yy << 10);
      for (int dx = 0; dx < r; ++dx) {
        int xx = x0 + dx;
        if ((unsigned)xx < 1024u) s += row[xx];
      }
    }
  }
  float inv = (r == 4) ? 0.0625f : (r == 2) ? 0.25f : 1.0f;
  phi[idx] = f2bf(s * inv);
}

// ---------------- GEMM1 (MFMA): partial1[kc][j*64+b] ----------------
// C[j][b] = sum_d W1[j][d] * phi[b][d]
// grid (8, KC1), block 256 (4 waves; wave w -> j-tile blockIdx.x*64+w*16)
__global__ __launch_bounds__(256) void gemm1_kernel(
    const short* __restrict__ phi, const float* __restrict__ W1,
    float* __restrict__ partial1) {
  int wave = threadIdx.x >> 6;
  int lane = threadIdx.x & 63;
  int lc = lane & 15;       // A: row=j ; B: col=b
  int kg = lane >> 4;       // k-group: k = kg*8 + i
  int j0 = blockIdx.x * 64 + wave * 16;
  int dbase = blockIdx.y * DCHUNK1;

  f32x4 acc[4] = {{0,0,0,0},{0,0,0,0},{0,0,0,0},{0,0,0,0}};

  const float* wrow = W1 + (size_t)(j0 + lc) * D_IN + kg * 8;
  const short* prow = phi + kg * 8;

  #pragma unroll
  for (int ks = 0; ks < DCHUNK1 / 32; ++ks) {
    int d0 = dbase + ks * 32;
    // A fragment: W1[j0+lc][d0 + kg*8 .. +8), fp32 -> bf16
    float4 wa = *(const float4*)(wrow + d0);
    float4 wb = *(const float4*)(wrow + d0 + 4);
    bf16x8 af;
    af[0] = f2bf(wa.x); af[1] = f2bf(wa.y); af[2] = f2bf(wa.z); af[3] = f2bf(wa.w);
    af[4] = f2bf(wb.x); af[5] = f2bf(wb.y); af[6] = f2bf(wb.z); af[7] = f2bf(wb.w);
    #pragma unroll
    for (int t = 0; t < 4; ++t) {
      // B fragment: phi[t*16+lc][d0 + kg*8 .. +8)
      bf16x8 bf = *(const bf16x8*)(prow + (size_t)(t * 16 + lc) * D_IN + d0);
      acc[t] = __builtin_amdgcn_mfma_f32_16x16x32_bf16(af, bf, acc[t], 0, 0, 0);
    }
  }

  float* pp = partial1 + (size_t)blockIdx.y * (HG0 * 64);
  #pragma unroll
  for (int t = 0; t < 4; ++t)
    #pragma unroll
    for (int r = 0; r < 4; ++r)
      pp[(size_t)(j0 + kg * 4 + r) * 64 + t * 16 + lc] = acc[t][r];
}

// ---------------- reduce1: sum split-K + leaky -> h_bf16[b][512] ----------------
__global__ __launch_bounds__(256) void reduce1_kernel(
    const float* __restrict__ partial1, short* __restrict__ h) {
  int idx = blockIdx.x * 256 + threadIdx.x;   // j*64 + b  (coalesced reads)
  float s = 0.0f;
  #pragma unroll 8
  for (int kc = 0; kc < KC1; ++kc) s += partial1[(size_t)kc * (HG0 * 64) + idx];
  float v = (s >= 0.0f) ? s : 0.01f * s;
  int j = idx >> 6, b = idx & 63;
  h[(size_t)b * HG0 + j] = f2bf(v);           // scattered 2B, only 64KB total
}

// ---------------- GEMM2 (MFMA): partial2[kc][b*1024+o] ----------------
// C[b][o] = sum_j h[b][j] * (W3[o][j]+W4[o][j])
// grid (64, KC2), block 64 (1 wave per block)
__global__ __launch_bounds__(64) void gemm2_kernel(
    const short* __restrict__ h, const float* __restrict__ W3,
    const float* __restrict__ W4, float* __restrict__ partial2) {
  int lane = threadIdx.x;
  int lc = lane & 15;       // A: row=b ; B: col=o
  int kg = lane >> 4;
  int o0 = blockIdx.x * 16;
  int jbase = blockIdx.y * DCHUNK2;

  f32x4 acc[4] = {{0,0,0,0},{0,0,0,0},{0,0,0,0},{0,0,0,0}};

  #pragma unroll
  for (int ks = 0; ks < DCHUNK2 / 32; ++ks) {
    int j0 = jbase + ks * 32;
    // B fragment: (W3+W4)[o0+lc][j0 + kg*8 .. +8)
    const float* w3r = W3 + (size_t)(o0 + lc) * HG0 + j0 + kg * 8;
    const float* w4r = W4 + (size_t)(o0 + lc) * HG0 + j0 + kg * 8;
    float4 a3 = *(const float4*)w3r;
    float4 b3 = *(const float4*)(w3r + 4);
    float4 a4 = *(const float4*)w4r;
    float4 b4 = *(const float4*)(w4r + 4);
    bf16x8 bf;
    bf[0] = f2bf(a3.x + a4.x); bf[1] = f2bf(a3.y + a4.y);
    bf[2] = f2bf(a3.z + a4.z); bf[3] = f2bf(a3.w + a4.w);
    bf[4] = f2bf(b3.x + b4.x); bf[5] = f2bf(b3.y + b4.y);
    bf[6] = f2bf(b3.z + b4.z); bf[7] = f2bf(b3.w + b4.w);
    #pragma unroll
    for (int t = 0; t < 4; ++t) {
      // A fragment: h[t*16+lc][j0 + kg*8 .. +8)
      bf16x8 af = *(const bf16x8*)(h + (size_t)(t * 16 + lc) * HG0 + j0 + kg * 8);
      acc[t] = __builtin_amdgcn_mfma_f32_16x16x32_bf16(af, bf, acc[t], 0, 0, 0);
    }
  }

  float* pp = partial2 + (size_t)blockIdx.y * (B_N * OUT_N);
  #pragma unroll
  for (int t = 0; t < 4; ++t)
    #pragma unroll
    for (int r = 0; r < 4; ++r)
      pp[(size_t)(t * 16 + kg * 4 + r) * OUT_N + o0 + lc] = acc[t][r];
}

// ---------------- reduce2: sum split-K + leaky -> out fp32 ----------------
__global__ __launch_bounds__(256) void reduce2_kernel(
    const float* __restrict__ partial2, float* __restrict__ out) {
  int idx = blockIdx.x * 256 + threadIdx.x;   // b*1024 + o
  float s = 0.0f;
  #pragma unroll
  for (int kc = 0; kc < KC2; ++kc) s += partial2[(size_t)kc * (B_N * OUT_N) + idx];
  out[idx] = (s >= 0.0f) ? s : 0.01f * s;
}

extern "C" void kernel_launch(void* const* d_in, const int* in_sizes, int n_in,
                              void* d_out, int out_size, void* d_ws, size_t ws_size,
                              hipStream_t stream) {
  const float* x  = (const float*)d_in[0];
  const float* l  = (const float*)d_in[1];
  const float* W1 = (const float*)d_in[2];
  const float* W3 = (const float*)d_in[4];
  const float* W4 = (const float*)d_in[5];
  float* out = (float*)d_out;

  char* ws = (char*)d_ws;
  short* phi      = (short*)(ws);                          // 64*12288*2   = 1.50 MB
  float* partial1 = (float*)(ws + (1u << 21));             // 64*512*64*4  = 8 MB
  short* h        = (short*)(ws + (1u << 21) + (1u << 23));// 64*512*2     = 64 KB
  float* partial2 = (float*)(ws + (1u << 21) + (1u << 23) + (1u << 17)); // 8*64*1024*4 = 2 MB

  foveate_kernel<<<dim3((B_N * D_IN) / 256), dim3(256), 0, stream>>>(x, l, phi);
  gemm1_kernel<<<dim3(8, KC1), dim3(256), 0, stream>>>(phi, W1, partial1);
  reduce1_kernel<<<dim3((HG0 * 64) / 256), dim3(256), 0, stream>>>(partial1, h);
  gemm2_kernel<<<dim3(OUT_N / 16, KC2), dim3(64), 0, stream>>>(h, W3, W4, partial2);
  reduce2_kernel<<<dim3((B_N * OUT_N) / 256), dim3(256), 0, stream>>>(partial2, out);
}

// Round 3
// 34.364 us; speedup vs baseline: 3.6095x; 1.0328x over previous
//
#include <hip/hip_runtime.h>
#include <hip/hip_bf16.h>

#define B_N 64
#define D_IN 12288      // K*G*G
#define HG0 512
#define OUT_N 1024      // HG0+HL

// GEMM1: grid (32 j-tiles, 16 kc); block = 4 waves, each wave covers 192 d
#define KC1 16
#define DBLOCK1 768     // per block (4 waves x 192)
#define DWAVE1 192      // 6 k-steps of 32

typedef __attribute__((ext_vector_type(8))) short bf16x8;
typedef __attribute__((ext_vector_type(4))) float f32x4;

static __device__ __forceinline__ short f2bf(float f) {
  __hip_bfloat16 h = __float2bfloat16(f);
  return *reinterpret_cast<short*>(&h);
}

// ---------------- Foveation -> phi_bf16[b][12288] ----------------
__global__ __launch_bounds__(256) void foveate_kernel(
    const float* __restrict__ x, const float* __restrict__ l,
    short* __restrict__ phi) {
  int idx = blockIdx.x * 256 + threadIdx.x;   // b*D_IN + d
  int b = idx / D_IN;
  int d = idx - b * D_IN;
  int k = d >> 12;
  int rem = d & 4095;
  int gy = rem >> 6, gx = rem & 63;

  float lx = l[b * 2 + 0];
  float ly = l[b * 2 + 1];
  int cx = (int)(0.5f * ((lx + 1.0f) * 1024.0f));   // trunc, matches .astype(int32)
  int cy = (int)(0.5f * ((ly + 1.0f) * 1024.0f));

  const float* xb = x + ((size_t)b << 20);
  float v;

  if (k == 0) {          // r=4, half=128
    int y0 = cy - 128 + gy * 4;
    int x0 = cx - 128 + gx * 4;
    float s = 0.0f;
    #pragma unroll
    for (int dy = 0; dy < 4; ++dy) {
      int yy = y0 + dy;
      if ((unsigned)yy < 1024u) {
        const float* row = xb + ((size_t)yy << 10);
        #pragma unroll
        for (int dx = 0; dx < 4; ++dx) {
          int xx = x0 + dx;
          if ((unsigned)xx < 1024u) s += row[xx];
        }
      }
    }
    v = s * 0.0625f;
  } else if (k == 1) {   // r=2, half=64
    int y0 = cy - 64 + gy * 2;
    int x0 = cx - 64 + gx * 2;
    float s = 0.0f;
    #pragma unroll
    for (int dy = 0; dy < 2; ++dy) {
      int yy = y0 + dy;
      if ((unsigned)yy < 1024u) {
        const float* row = xb + ((size_t)yy << 10);
        #pragma unroll
        for (int dx = 0; dx < 2; ++dx) {
          int xx = x0 + dx;
          if ((unsigned)xx < 1024u) s += row[xx];
        }
      }
    }
    v = s * 0.25f;
  } else {               // r=1, half=32
    int yy = cy - 32 + gy;
    int xx = cx - 32 + gx;
    v = 0.0f;
    if ((unsigned)yy < 1024u && (unsigned)xx < 1024u) v = xb[((size_t)yy << 10) + xx];
  }
  phi[idx] = f2bf(v);
}

// ---------------- GEMM1 (MFMA, block split-K): partial1[kc][j*64+b] ----------------
// C[j][b] = sum_d W1[j][d] * phi[b][d]
// grid (32, KC1), block 256: wave w covers d-chunk blockIdx.y*768 + w*192
__global__ __launch_bounds__(256) void gemm1_kernel(
    const short* __restrict__ phi, const float* __restrict__ W1,
    float* __restrict__ partial1) {
  __shared__ float lds[4 * 16 * 64];   // [wave][j_local][b] 16KB
  int wave = threadIdx.x >> 6;
  int lane = threadIdx.x & 63;
  int lc = lane & 15;       // A row = j ; B col = b
  int kg = lane >> 4;
  int j0 = blockIdx.x * 16;
  int dbase = blockIdx.y * DBLOCK1 + wave * DWAVE1;

  f32x4 acc[4] = {{0,0,0,0},{0,0,0,0},{0,0,0,0},{0,0,0,0}};

  const float* wrow = W1 + (size_t)(j0 + lc) * D_IN + kg * 8;
  const short* prow = phi + kg * 8;

  #pragma unroll
  for (int ks = 0; ks < DWAVE1 / 32; ++ks) {
    int d0 = dbase + ks * 32;
    float4 wa = *(const float4*)(wrow + d0);
    float4 wb = *(const float4*)(wrow + d0 + 4);
    bf16x8 af;
    af[0] = f2bf(wa.x); af[1] = f2bf(wa.y); af[2] = f2bf(wa.z); af[3] = f2bf(wa.w);
    af[4] = f2bf(wb.x); af[5] = f2bf(wb.y); af[6] = f2bf(wb.z); af[7] = f2bf(wb.w);
    #pragma unroll
    for (int t = 0; t < 4; ++t) {
      bf16x8 bf = *(const bf16x8*)(prow + (size_t)(t * 16 + lc) * D_IN + d0);
      acc[t] = __builtin_amdgcn_mfma_f32_16x16x32_bf16(af, bf, acc[t], 0, 0, 0);
    }
  }

  // stash per-wave results: lds[w][j_local = kg*4+r][b = t*16+lc]
  #pragma unroll
  for (int t = 0; t < 4; ++t)
    #pragma unroll
    for (int r = 0; r < 4; ++r)
      lds[wave * 1024 + (kg * 4 + r) * 64 + t * 16 + lc] = acc[t][r];
  __syncthreads();

  // reduce 4 waves -> partial1 (coalesced: e = tid + 256*i)
  float* pp = partial1 + (size_t)blockIdx.y * (HG0 * 64) + (size_t)j0 * 64;
  #pragma unroll
  for (int i = 0; i < 4; ++i) {
    int e = threadIdx.x + 256 * i;
    float s = lds[e] + lds[1024 + e] + lds[2048 + e] + lds[3072 + e];
    pp[e] = s;
  }
}

// ---------------- reduce1: sum split-K + leaky -> h_bf16[b][512] ----------------
__global__ __launch_bounds__(256) void reduce1_kernel(
    const float* __restrict__ partial1, short* __restrict__ h) {
  int idx = blockIdx.x * 256 + threadIdx.x;   // j*64 + b
  float s = 0.0f;
  #pragma unroll
  for (int kc = 0; kc < KC1; ++kc) s += partial1[(size_t)kc * (HG0 * 64) + idx];
  float v = (s >= 0.0f) ? s : 0.01f * s;
  int j = idx >> 6, b = idx & 63;
  h[(size_t)b * HG0 + j] = f2bf(v);
}

// ---------------- GEMM2 fused (MFMA + block split-K + lrelu) ----------------
// out[b][o] = lrelu( sum_j h[b][j] * (W3[o][j]+W4[o][j]) )
// grid (64), block 256: wave w covers j-chunk w*128..+128
__global__ __launch_bounds__(256) void gemm2_kernel(
    const short* __restrict__ h, const float* __restrict__ W3,
    const float* __restrict__ W4, float* __restrict__ out) {
  __shared__ float lds[4 * 1024];   // [wave][e] 16KB
  int wave = threadIdx.x >> 6;
  int lane = threadIdx.x & 63;
  int lc = lane & 15;       // B col = o
  int kg = lane >> 4;
  int o0 = blockIdx.x * 16;
  int jbase = wave * 128;

  f32x4 acc[4] = {{0,0,0,0},{0,0,0,0},{0,0,0,0},{0,0,0,0}};

  #pragma unroll
  for (int ks = 0; ks < 4; ++ks) {
    int j0 = jbase + ks * 32;
    const float* w3r = W3 + (size_t)(o0 + lc) * HG0 + j0 + kg * 8;
    const float* w4r = W4 + (size_t)(o0 + lc) * HG0 + j0 + kg * 8;
    float4 a3 = *(const float4*)w3r;
    float4 b3 = *(const float4*)(w3r + 4);
    float4 a4 = *(const float4*)w4r;
    float4 b4 = *(const float4*)(w4r + 4);
    bf16x8 bf;
    bf[0] = f2bf(a3.x + a4.x); bf[1] = f2bf(a3.y + a4.y);
    bf[2] = f2bf(a3.z + a4.z); bf[3] = f2bf(a3.w + a4.w);
    bf[4] = f2bf(b3.x + b4.x); bf[5] = f2bf(b3.y + b4.y);
    bf[6] = f2bf(b3.z + b4.z); bf[7] = f2bf(b3.w + b4.w);
    #pragma unroll
    for (int t = 0; t < 4; ++t) {
      bf16x8 af = *(const bf16x8*)(h + (size_t)(t * 16 + lc) * HG0 + j0 + kg * 8);
      acc[t] = __builtin_amdgcn_mfma_f32_16x16x32_bf16(af, bf, acc[t], 0, 0, 0);
    }
  }

  // acc[t][r] = C[b = t*16 + kg*4 + r][o = o0 + lc]
  // lds[w][e], e = t*256 + kg*64 + r*16 + lc
  #pragma unroll
  for (int t = 0; t < 4; ++t)
    #pragma unroll
    for (int r = 0; r < 4; ++r)
      lds[wave * 1024 + t * 256 + kg * 64 + r * 16 + lc] = acc[t][r];
  __syncthreads();

  #pragma unroll
  for (int i = 0; i < 4; ++i) {
    int e = threadIdx.x + 256 * i;
    float s = lds[e] + lds[1024 + e] + lds[2048 + e] + lds[3072 + e];
    float v = (s >= 0.0f) ? s : 0.01f * s;
    int b = ((e >> 8) << 4) + (((e >> 6) & 3) << 2) + ((e >> 4) & 3);
    out[(size_t)b * OUT_N + o0 + (e & 15)] = v;
  }
}

extern "C" void kernel_launch(void* const* d_in, const int* in_sizes, int n_in,
                              void* d_out, int out_size, void* d_ws, size_t ws_size,
                              hipStream_t stream) {
  const float* x  = (const float*)d_in[0];
  const float* l  = (const float*)d_in[1];
  const float* W1 = (const float*)d_in[2];
  const float* W3 = (const float*)d_in[4];
  const float* W4 = (const float*)d_in[5];
  float* out = (float*)d_out;

  char* ws = (char*)d_ws;
  short* phi      = (short*)(ws);                          // 64*12288*2 = 1.5 MB
  float* partial1 = (float*)(ws + (1u << 21));             // 16*512*64*4 = 2 MB
  short* h        = (short*)(ws + (1u << 21) + (1u << 22)); // 64*512*2 = 64 KB

  foveate_kernel<<<dim3((B_N * D_IN) / 256), dim3(256), 0, stream>>>(x, l, phi);
  gemm1_kernel<<<dim3(32, KC1), dim3(256), 0, stream>>>(phi, W1, partial1);
  reduce1_kernel<<<dim3((HG0 * 64) / 256), dim3(256), 0, stream>>>(partial1, h);
  gemm2_kernel<<<dim3(OUT_N / 16), dim3(256), 0, stream>>>(h, W3, W4, out);
}